// Round 10
// baseline (180.343 us; speedup 1.0000x reference)
//
#include <hip/hip_runtime.h>

// BuildCombinationsDim2: out[b,t,j] = x[b,t, idx[j]] where idx is the
// flattened list of k=2 combinations of F=32 features (lexicographic).
// ncr = 2*C(32,2) = 992. Pure gather along last axis; write-BW-bound.
// R10: fill-occupancy clone with per-wave contiguous bursts. 256 blocks
// (1/CU, 1024 waves ~= fill's 11% occupancy), no loop barriers; each
// wave writes 8 back-to-back 1 KB stores (8 KB contiguous burst) per
// outer iteration; chip window = compact 8 MB front; 62 exact iters.
// Feat table precomputed once into LDS (packed bytes). Plain stores.

#define FDIM 32
#define NCR 992            // k * C(F,2)
#define G_PER_ROW 248      // NCR / 4 f32x4 groups per row
#define BLOCK 256
#define GRID 256           // 1 block/CU -> 1024 waves, fill-like
#define UNROLL 8

typedef float f32x4 __attribute__((ext_vector_type(4)));

__global__ __launch_bounds__(BLOCK)
void comb_gather_kernel(const float* __restrict__ x,
                        float* __restrict__ out,
                        int nrows) {
    __shared__ int featp[G_PER_ROW];   // packed f0|f1<<8|f2<<16|f3<<24

    const int tid = threadIdx.x;

    // Build the 248-entry gather table once per block (closed-form
    // inversion of start(i) = i*(63-i)/2 with +-1 integer fixup).
    if (tid < G_PER_ROW) {
        const int c0 = 2 * tid;
        float s = sqrtf(3969.0f - 8.0f * (float)c0);
        int i0 = (int)((63.0f - s) * 0.5f);
        if (i0 < 0) i0 = 0;
        int st0  = (i0 * (63 - i0)) >> 1;
        int stn0 = ((i0 + 1) * (62 - i0)) >> 1;
        if (stn0 <= c0) { i0++; st0 = stn0; stn0 = ((i0 + 1) * (62 - i0)) >> 1; }
        else if (st0 > c0) { i0--; stn0 = st0; st0 = (i0 * (63 - i0)) >> 1; }
        const int f0 = i0;
        const int f1 = c0 - st0 + i0 + 1;
        const int c1 = c0 + 1;
        int i1 = i0, st1 = st0;
        if (stn0 <= c1) { i1 = i0 + 1; st1 = stn0; }
        const int f2 = i1;
        const int f3 = c1 - st1 + i1 + 1;
        featp[tid] = f0 | (f1 << 8) | (f2 << 16) | (f3 << 24);
    }
    __syncthreads();

    const unsigned T    = (unsigned)nrows * G_PER_ROW;      // total f32x4 groups
    const unsigned gtid = blockIdx.x * BLOCK + tid;
    const unsigned wave = gtid >> 6;                        // global wave id
    const unsigned lane = gtid & 63;
    const unsigned nw   = (GRID * BLOCK) >> 6;              // 1024 waves
    const unsigned wstep = UNROLL * 64;                     // groups per wave/iter
    const unsigned step  = nw * wstep;                      // 524288 (8 MB window)

    f32x4* outv = reinterpret_cast<f32x4*>(out);
    const unsigned G0 = wave * wstep + lane;

    for (unsigned base = G0; base < T; base += step) {
        if (base + (UNROLL - 1) * 64 < T) {
            // Fast path: 8 back-to-back 1 KB wave stores, contiguous 8 KB.
            #pragma unroll
            for (int u = 0; u < UNROLL; ++u) {
                const unsigned G   = base + u * 64;
                const unsigned row = G / G_PER_ROW;          // magic-mul
                const unsigned g   = G - row * G_PER_ROW;
                const int p = featp[g];                      // conflict-free
                const float* rowp = x + (size_t)row * FDIM;  // L1/L2-hit
                f32x4 v;
                v.x = rowp[p & 0xff];
                v.y = rowp[(p >> 8) & 0xff];
                v.z = rowp[(p >> 16) & 0xff];
                v.w = rowp[(p >> 24) & 0xff];
                outv[G] = v;                                 // plain store
            }
        } else {
            #pragma unroll
            for (int u = 0; u < UNROLL; ++u) {
                const unsigned G = base + u * 64;
                if (G < T) {
                    const unsigned row = G / G_PER_ROW;
                    const unsigned g   = G - row * G_PER_ROW;
                    const int p = featp[g];
                    const float* rowp = x + (size_t)row * FDIM;
                    f32x4 v;
                    v.x = rowp[p & 0xff];
                    v.y = rowp[(p >> 8) & 0xff];
                    v.z = rowp[(p >> 16) & 0xff];
                    v.w = rowp[(p >> 24) & 0xff];
                    outv[G] = v;
                }
            }
        }
    }
}

extern "C" void kernel_launch(void* const* d_in, const int* in_sizes, int n_in,
                              void* d_out, int out_size, void* d_ws, size_t ws_size,
                              hipStream_t stream) {
    const float* x  = (const float*)d_in[0];
    float* out      = (float*)d_out;
    int nrows = in_sizes[0] / FDIM;                       // 32*4096 = 131072
    hipLaunchKernelGGL(comb_gather_kernel, dim3(GRID), dim3(BLOCK), 0, stream,
                       x, out, nrows);
}

// Round 11
// 109.328 us; speedup vs baseline: 1.6496x; 1.6496x over previous
//
#include <hip/hip_runtime.h>

// BuildCombinationsDim2: out[b,t,j] = x[b,t, idx[j]] where idx is the
// flattened list of k=2 combinations of F=32 features (lexicographic).
// ncr = 2*C(32,2) = 992. Pure gather along last axis; write-BW-bound.
// R11: R8 (full-occupancy grid-stride, nt stores) with ONE change:
// per-wave store-burst adjacency. Each wave writes 8 consecutive 1 KB
// wave-stores (one contiguous 8 KB burst) per outer iteration instead
// of 1 KB bursts 8 MB apart. Total groups = 63488 * 512, so every wave
// does exact full bursts - no tail. Isolates DRAM burst adjacency.

#define FDIM 32
#define NCR 992            // k * C(F,2)
#define G_PER_ROW 248      // NCR / 4 f32x4 groups per row
#define BLOCK 256
#define GRID 2048          // 8 blocks/CU -> full residency (R8-equal)
#define UNROLL 8           // 8 x 1 KB consecutive wave stores = 8 KB burst

typedef float f32x4 __attribute__((ext_vector_type(4)));

__global__ __launch_bounds__(BLOCK, 8)
void comb_gather_kernel(const float* __restrict__ x,
                        float* __restrict__ out,
                        int nrows) {
    const unsigned T    = (unsigned)nrows * G_PER_ROW;   // 32,505,856 groups
    const unsigned gtid = blockIdx.x * BLOCK + threadIdx.x;
    const unsigned wave = gtid >> 6;                     // global wave id
    const unsigned lane = gtid & 63;
    const unsigned nw   = (GRID * BLOCK) >> 6;           // 8192 waves
    const unsigned wspan = UNROLL * 64;                  // 512 groups per burst
    const unsigned step  = nw * wspan;                   // 4,194,304 groups/iter

    f32x4* outv = reinterpret_cast<f32x4*>(out);

    for (unsigned base = wave * wspan; base < T; base += step) {
        if (base + wspan <= T) {
            // 8 back-to-back 1 KB wave stores: contiguous 8 KB burst.
            #pragma unroll
            for (int u = 0; u < UNROLL; ++u) {
                const unsigned G   = base + u * 64 + lane;
                const unsigned row = G / G_PER_ROW;      // magic-mul
                const unsigned g   = G - row * G_PER_ROW;

                // Closed-form inversion of start(i)=i*(63-i)/2, +-1 fixup.
                const int c0 = 2 * (int)g;
                float s = sqrtf(3969.0f - 8.0f * (float)c0);
                int i0 = (int)((63.0f - s) * 0.5f);
                if (i0 < 0) i0 = 0;
                int st0  = (i0 * (63 - i0)) >> 1;
                int stn0 = ((i0 + 1) * (62 - i0)) >> 1;
                if (stn0 <= c0) { i0++; st0 = stn0; stn0 = ((i0 + 1) * (62 - i0)) >> 1; }
                else if (st0 > c0) { i0--; stn0 = st0; st0 = (i0 * (63 - i0)) >> 1; }
                const int f0 = i0;
                const int f1 = c0 - st0 + i0 + 1;
                const int c1 = c0 + 1;
                int i1 = i0, st1 = st0;
                if (stn0 <= c1) { i1 = i0 + 1; st1 = stn0; }
                const int f2 = i1;
                const int f3 = c1 - st1 + i1 + 1;

                const float* rowp = x + (size_t)row * FDIM;   // L1/L2-hit
                f32x4 v;
                v.x = rowp[f0];
                v.y = rowp[f1];
                v.z = rowp[f2];
                v.w = rowp[f3];
                __builtin_nontemporal_store(v, outv + G);
            }
        } else {
            for (int u = 0; u < UNROLL; ++u) {
                const unsigned G = base + u * 64 + lane;
                if (G < T) {
                    const unsigned row = G / G_PER_ROW;
                    const unsigned g   = G - row * G_PER_ROW;
                    const int c0 = 2 * (int)g;
                    float s = sqrtf(3969.0f - 8.0f * (float)c0);
                    int i0 = (int)((63.0f - s) * 0.5f);
                    if (i0 < 0) i0 = 0;
                    int st0  = (i0 * (63 - i0)) >> 1;
                    int stn0 = ((i0 + 1) * (62 - i0)) >> 1;
                    if (stn0 <= c0) { i0++; st0 = stn0; stn0 = ((i0 + 1) * (62 - i0)) >> 1; }
                    else if (st0 > c0) { i0--; stn0 = st0; st0 = (i0 * (63 - i0)) >> 1; }
                    const int f0 = i0;
                    const int f1 = c0 - st0 + i0 + 1;
                    const int c1 = c0 + 1;
                    int i1 = i0, st1 = st0;
                    if (stn0 <= c1) { i1 = i0 + 1; st1 = stn0; }
                    const int f2 = i1;
                    const int f3 = c1 - st1 + i1 + 1;
                    const float* rowp = x + (size_t)row * FDIM;
                    f32x4 v;
                    v.x = rowp[f0];
                    v.y = rowp[f1];
                    v.z = rowp[f2];
                    v.w = rowp[f3];
                    __builtin_nontemporal_store(v, outv + G);
                }
            }
        }
    }
}

extern "C" void kernel_launch(void* const* d_in, const int* in_sizes, int n_in,
                              void* d_out, int out_size, void* d_ws, size_t ws_size,
                              hipStream_t stream) {
    const float* x  = (const float*)d_in[0];
    float* out      = (float*)d_out;
    int nrows = in_sizes[0] / FDIM;                       // 32*4096 = 131072
    hipLaunchKernelGGL(comb_gather_kernel, dim3(GRID), dim3(BLOCK), 0, stream,
                       x, out, nrows);
}

// Round 12
// 100.745 us; speedup vs baseline: 1.7901x; 1.0852x over previous
//
#include <hip/hip_runtime.h>

// BuildCombinationsDim2: out[b,t,j] = x[b,t, idx[j]] where idx is the
// flattened list of k=2 combinations of F=32 features (lexicographic).
// ncr = 2*C(32,2) = 992. Pure gather along last axis; write-BW-bound.
// FINAL (= R4, best of 11 variants at 101.4 us ~= 5.3 TB/s):
// LDS-staged 16 rows/block, closed-form combination inversion,
// nt float4 stores. R5-R11 refuted every alternative mechanism
// (stream count, read interleave, front compactness, burst adjacency,
// store flags, occupancy) -- all land 101-110 us; this is the practical
// memory-system ceiling for gather-fed streaming writes (537 MB
// mandatory traffic; fill=6.9 TB/s and copy=6.3 TB/s are pure-stream
// upper references unreachable with per-store gather dependency +
// ~10 us fixed launch overhead at this problem scale).

#define FDIM 32
#define NCR 992            // k * C(F,2)
#define G_PER_ROW 248      // NCR / 4 float4 groups per row
#define ROWS_PER_BLOCK 16
#define BLOCK 256

typedef float f32x4 __attribute__((ext_vector_type(4)));
typedef float f32x2 __attribute__((ext_vector_type(2)));

__global__ __launch_bounds__(BLOCK)
void comb_gather_kernel(const float* __restrict__ x,
                        float* __restrict__ out,
                        int nrows) {
    __shared__ float lds[ROWS_PER_BLOCK * FDIM];   // 16 rows * 32 f32 = 2 KB

    const int tid  = threadIdx.x;
    const int row0 = blockIdx.x * ROWS_PER_BLOCK;
    const bool full = (row0 + ROWS_PER_BLOCK) <= nrows;

    // Stage 16 input rows (512 floats = 256 float2) into LDS, coalesced.
    {
        const f32x2* src = reinterpret_cast<const f32x2*>(x + (size_t)row0 * FDIM);
        if (full) {
            reinterpret_cast<f32x2*>(lds)[tid] = src[tid];
        } else {
            int row_of_load = row0 + (tid * 2) / FDIM;
            if (row_of_load < nrows)
                reinterpret_cast<f32x2*>(lds)[tid] = src[tid];
        }
    }

    // Thread g owns output float4 group g: columns j = 4g..4g+3.
    // j -> combination c = 2g + (u>>1), position j&1. Closed-form
    // inversion of start(i) = i*(63-i)/2 with +-1 integer fixup.
    int feat[4];
    const int g = tid;
    if (g < G_PER_ROW) {
        const int c0 = 2 * g;
        float s = sqrtf(3969.0f - 8.0f * (float)c0);
        int i0 = (int)((63.0f - s) * 0.5f);
        if (i0 < 0) i0 = 0;
        int st0  = (i0 * (63 - i0)) >> 1;
        int stn0 = ((i0 + 1) * (62 - i0)) >> 1;
        if (stn0 <= c0) { i0++; st0 = stn0; stn0 = ((i0 + 1) * (62 - i0)) >> 1; }
        else if (st0 > c0) { i0--; stn0 = st0; st0 = (i0 * (63 - i0)) >> 1; }
        feat[0] = i0;
        feat[1] = c0 - st0 + i0 + 1;
        const int c1 = c0 + 1;
        int i1 = i0, st1 = st0;
        if (stn0 <= c1) { i1 = i0 + 1; st1 = stn0; }
        feat[2] = i1;
        feat[3] = c1 - st1 + i1 + 1;
    }
    __syncthreads();

    if (g >= G_PER_ROW) return;

    if (full) {
        f32x4* outp = reinterpret_cast<f32x4*>(out + (size_t)row0 * NCR) + g;
        #pragma unroll
        for (int r = 0; r < ROWS_PER_BLOCK; ++r) {
            const float* rowp = lds + r * FDIM;   // same row across lanes
            f32x4 v;
            v.x = rowp[feat[0]];
            v.y = rowp[feat[1]];
            v.z = rowp[feat[2]];
            v.w = rowp[feat[3]];
            __builtin_nontemporal_store(v, outp);  // stream past L2
            outp += NCR / 4;
        }
    } else {
        #pragma unroll
        for (int r = 0; r < ROWS_PER_BLOCK; ++r) {
            int row = row0 + r;
            if (row >= nrows) break;
            const float* rowp = lds + r * FDIM;
            f32x4 v;
            v.x = rowp[feat[0]];
            v.y = rowp[feat[1]];
            v.z = rowp[feat[2]];
            v.w = rowp[feat[3]];
            __builtin_nontemporal_store(
                v, reinterpret_cast<f32x4*>(out + (size_t)row * NCR) + g);
        }
    }
}

extern "C" void kernel_launch(void* const* d_in, const int* in_sizes, int n_in,
                              void* d_out, int out_size, void* d_ws, size_t ws_size,
                              hipStream_t stream) {
    const float* x  = (const float*)d_in[0];
    float* out      = (float*)d_out;
    int nrows = in_sizes[0] / FDIM;                       // 32*4096 = 131072
    int grid  = (nrows + ROWS_PER_BLOCK - 1) / ROWS_PER_BLOCK;  // 8192
    hipLaunchKernelGGL(comb_gather_kernel, dim3(grid), dim3(BLOCK), 0, stream,
                       x, out, nrows);
}